// Round 1
// baseline (286.529 us; speedup 1.0000x reference)
//
#include <hip/hip_runtime.h>
#include <math.h>

#define BB 32
#define TT 4096
#define DD 768
#define NH 4
#define DK 64
#define DV 64
#define RELW 32
#define NREL 65
#define HIDDEN 256
#define INPROJ 1792  // DD + NH*DV + DD

#define TB 16        // t-rows per block in scores pass
#define NCHUNK 16    // t-chunks per batch in weighted-sum pass
#define TCHUNK 256   // TT / NCHUNK

// ---------------- kernel A: h_i gather, Q = h_i·WQ, qk = (Q·WK)/8 ----------------
__global__ __launch_bounds__(256) void kA(const float* __restrict__ H,
                                          const int* __restrict__ noun_pos,
                                          const float* __restrict__ WQ,
                                          const float* __restrict__ WK,
                                          float* __restrict__ hi_ws,
                                          float* __restrict__ qk_ws) {
    int b = blockIdx.x / NH, h = blockIdx.x % NH;
    __shared__ float hi_s[DD];
    __shared__ float q_s[DK];
    int tn = noun_pos[b];
    const float* Hrow = H + ((size_t)b * TT + tn) * DD;
    for (int d = threadIdx.x; d < DD; d += 256) {
        float v = Hrow[d];
        hi_s[d] = v;
        if (h == 0) hi_ws[b * DD + d] = v;
    }
    __syncthreads();
    if (threadIdx.x < DK) {
        int k = threadIdx.x;
        const float* wq = WQ + (size_t)h * DD * DK + k;
        float acc = 0.f;
        for (int d = 0; d < DD; ++d) acc += hi_s[d] * wq[(size_t)d * DK];
        q_s[k] = acc;
    }
    __syncthreads();
    for (int d = threadIdx.x; d < DD; d += 256) {
        const float* wk = WK + ((size_t)h * DD + d) * DK;
        float acc = 0.f;
        #pragma unroll
        for (int k = 0; k < DK; ++k) acc += q_s[k] * wk[k];
        qk_ws[((size_t)b * NH + h) * DD + d] = acc * 0.125f;  // 1/sqrt(64)
    }
}

// ---------------- kernel B: scores[b,h,t] = H[b,t,:]·qk[b,h,:] + rb, masked ----------------
__global__ __launch_bounds__(256) void kB(const float* __restrict__ H,
                                          const int* __restrict__ mask,
                                          const int* __restrict__ noun_pos,
                                          const float* __restrict__ rel_bias,
                                          const float* __restrict__ qk_ws,
                                          float* __restrict__ scores) {
    int b = blockIdx.x / (TT / TB);
    int chunk = blockIdx.x % (TT / TB);
    __shared__ float qk_s[NH][DD];
    __shared__ float rb_s[NH][NREL];
    for (int i = threadIdx.x; i < NH * DD; i += 256)
        ((float*)qk_s)[i] = qk_ws[(size_t)b * NH * DD + i];
    for (int i = threadIdx.x; i < NH * NREL; i += 256)
        ((float*)rb_s)[i] = rel_bias[i];
    __syncthreads();
    int wave = threadIdx.x >> 6, lane = threadIdx.x & 63;
    int tn = noun_pos[b];
    for (int r = 0; r < TB / 4; ++r) {
        int t = chunk * TB + r * 4 + wave;
        const float4* Hrow = (const float4*)(H + ((size_t)b * TT + t) * DD);
        float s0 = 0.f, s1 = 0.f, s2 = 0.f, s3 = 0.f;
        #pragma unroll
        for (int j = 0; j < 3; ++j) {
            int idx = lane + 64 * j;
            float4 hv = Hrow[idx];
            float4 q0 = ((const float4*)qk_s[0])[idx];
            float4 q1 = ((const float4*)qk_s[1])[idx];
            float4 q2 = ((const float4*)qk_s[2])[idx];
            float4 q3 = ((const float4*)qk_s[3])[idx];
            s0 += hv.x * q0.x + hv.y * q0.y + hv.z * q0.z + hv.w * q0.w;
            s1 += hv.x * q1.x + hv.y * q1.y + hv.z * q1.z + hv.w * q1.w;
            s2 += hv.x * q2.x + hv.y * q2.y + hv.z * q2.z + hv.w * q2.w;
            s3 += hv.x * q3.x + hv.y * q3.y + hv.z * q3.z + hv.w * q3.w;
        }
        #pragma unroll
        for (int off = 32; off; off >>= 1) {
            s0 += __shfl_xor(s0, off);
            s1 += __shfl_xor(s1, off);
            s2 += __shfl_xor(s2, off);
            s3 += __shfl_xor(s3, off);
        }
        if (lane < NH) {
            float s = (lane == 0) ? s0 : (lane == 1) ? s1 : (lane == 2) ? s2 : s3;
            int m = mask[(size_t)b * TT + t];
            int delta = t - tn;
            delta = delta < -RELW ? -RELW : (delta > RELW ? RELW : delta);
            float val = m ? (s + rb_s[lane][delta + RELW]) : -1e9f;
            scores[((size_t)b * NH + lane) * TT + t] = val;
        }
    }
}

// ---------------- softmax over T, in place ----------------
__global__ __launch_bounds__(256) void kSM(float* __restrict__ scores) {
    float* row = scores + (size_t)blockIdx.x * TT;
    float vals[16];
    float m = -INFINITY;
    #pragma unroll
    for (int i = 0; i < 16; ++i) {
        vals[i] = row[threadIdx.x + 256 * i];
        m = fmaxf(m, vals[i]);
    }
    #pragma unroll
    for (int off = 32; off; off >>= 1) m = fmaxf(m, __shfl_xor(m, off));
    __shared__ float redm[4];
    if ((threadIdx.x & 63) == 0) redm[threadIdx.x >> 6] = m;
    __syncthreads();
    m = fmaxf(fmaxf(redm[0], redm[1]), fmaxf(redm[2], redm[3]));
    float l = 0.f;
    #pragma unroll
    for (int i = 0; i < 16; ++i) {
        vals[i] = expf(vals[i] - m);
        l += vals[i];
    }
    #pragma unroll
    for (int off = 32; off; off >>= 1) l += __shfl_xor(l, off);
    __shared__ float redl[4];
    if ((threadIdx.x & 63) == 0) redl[threadIdx.x >> 6] = l;
    __syncthreads();
    l = redl[0] + redl[1] + redl[2] + redl[3];
    float inv = 1.f / l;
    #pragma unroll
    for (int i = 0; i < 16; ++i) row[threadIdx.x + 256 * i] = vals[i] * inv;
}

// ---------------- kernel C: partial hbar[b,c,h,d] = sum_{t in chunk} alpha*H ----------------
__global__ __launch_bounds__(192) void kC(const float* __restrict__ H,
                                          const float* __restrict__ alpha,
                                          float* __restrict__ part) {
    int b = blockIdx.x / NCHUNK;
    int chunk = blockIdx.x % NCHUNK;
    __shared__ float a_s[NH][TCHUNK];
    for (int i = threadIdx.x; i < NH * TCHUNK; i += 192) {
        int h = i / TCHUNK, tt = i % TCHUNK;
        a_s[h][tt] = alpha[((size_t)b * NH + h) * TT + chunk * TCHUNK + tt];
    }
    __syncthreads();
    float4 acc[NH];
    #pragma unroll
    for (int h = 0; h < NH; ++h) acc[h] = make_float4(0.f, 0.f, 0.f, 0.f);
    const float4* Hbase = (const float4*)(H + ((size_t)b * TT + chunk * TCHUNK) * DD);
    #pragma unroll 4
    for (int tt = 0; tt < TCHUNK; ++tt) {
        float4 hv = Hbase[(size_t)tt * (DD / 4) + threadIdx.x];
        #pragma unroll
        for (int h = 0; h < NH; ++h) {
            float a = a_s[h][tt];
            acc[h].x += a * hv.x;
            acc[h].y += a * hv.y;
            acc[h].z += a * hv.z;
            acc[h].w += a * hv.w;
        }
    }
    #pragma unroll
    for (int h = 0; h < NH; ++h)
        ((float4*)(part + ((size_t)blockIdx.x * NH + h) * DD))[threadIdx.x] = acc[h];
}

// ---------------- combine partials ----------------
__global__ __launch_bounds__(256) void kComb(const float* __restrict__ part,
                                             float* __restrict__ hbar) {
    int i = blockIdx.x * 256 + threadIdx.x;  // over BB*NH*DD
    int b = i / (NH * DD);
    int hd = i % (NH * DD);
    float acc = 0.f;
    #pragma unroll
    for (int c = 0; c < NCHUNK; ++c)
        acc += part[(size_t)(b * NCHUNK + c) * NH * DD + hd];
    hbar[i] = acc;
}

// ---------------- transpose proj_w (HIDDEN,INPROJ) -> (INPROJ,HIDDEN) ----------------
__global__ __launch_bounds__(256) void kT(const float* __restrict__ pw,
                                          float* __restrict__ pwT) {
    int o = blockIdx.x * 256 + threadIdx.x;  // coalesced read
    int j = o / INPROJ, i = o % INPROJ;
    pwT[(size_t)i * HIDDEN + j] = pw[o];
}

// ---------------- kernel D: c = hbar·WV, concat, GELU MLP, logits ----------------
__global__ __launch_bounds__(256) void kD(const float* __restrict__ hbar,
                                          const float* __restrict__ hi_ws,
                                          const float* __restrict__ pooled,
                                          const float* __restrict__ WV,
                                          const float* __restrict__ pwT,
                                          const float* __restrict__ pb,
                                          const float* __restrict__ mw,
                                          const float* __restrict__ mb,
                                          float* __restrict__ out) {
    int b = blockIdx.x;
    __shared__ float r_s[INPROJ];
    __shared__ float hb_s[NH * DD];
    __shared__ float hdn_s[HIDDEN];
    for (int i = threadIdx.x; i < NH * DD; i += 256) hb_s[i] = hbar[(size_t)b * NH * DD + i];
    for (int i = threadIdx.x; i < DD; i += 256) {
        r_s[i] = hi_ws[b * DD + i];
        r_s[DD + NH * DV + i] = pooled[b * DD + i];
    }
    __syncthreads();
    {   // c[h][v]; thread = h*64+v — coalesced WV reads across lanes
        int h = threadIdx.x >> 6, v = threadIdx.x & 63;
        const float* wv = WV + (size_t)h * DD * DV + v;
        const float* hb = hb_s + h * DD;
        float acc = 0.f;
        for (int d = 0; d < DD; ++d) acc += hb[d] * wv[(size_t)d * DV];
        r_s[DD + threadIdx.x] = acc;
    }
    __syncthreads();
    {   // hidden j = tid; coalesced pwT reads
        int j = threadIdx.x;
        float acc = pb[j];
        #pragma unroll 8
        for (int i = 0; i < INPROJ; ++i) acc += r_s[i] * pwT[(size_t)i * HIDDEN + j];
        hdn_s[j] = 0.5f * acc * (1.f + erff(acc * 0.70710678118654752f));
    }
    __syncthreads();
    float p0 = hdn_s[threadIdx.x] * mw[threadIdx.x];
    float p1 = hdn_s[threadIdx.x] * mw[HIDDEN + threadIdx.x];
    #pragma unroll
    for (int off = 32; off; off >>= 1) {
        p0 += __shfl_xor(p0, off);
        p1 += __shfl_xor(p1, off);
    }
    __shared__ float r0[4], r1[4];
    if ((threadIdx.x & 63) == 0) {
        r0[threadIdx.x >> 6] = p0;
        r1[threadIdx.x >> 6] = p1;
    }
    __syncthreads();
    if (threadIdx.x == 0) {
        out[b * 2 + 0] = r0[0] + r0[1] + r0[2] + r0[3] + mb[0];
        out[b * 2 + 1] = r1[0] + r1[1] + r1[2] + r1[3] + mb[1];
    }
}

extern "C" void kernel_launch(void* const* d_in, const int* in_sizes, int n_in,
                              void* d_out, int out_size, void* d_ws, size_t ws_size,
                              hipStream_t stream) {
    const float* H      = (const float*)d_in[0];
    const int*   mask   = (const int*)d_in[1];
    const int*   noun   = (const int*)d_in[2];
    const float* pooled = (const float*)d_in[3];
    const float* WQ     = (const float*)d_in[4];
    const float* WK     = (const float*)d_in[5];
    const float* WV     = (const float*)d_in[6];
    const float* relb   = (const float*)d_in[7];
    const float* pw     = (const float*)d_in[8];
    const float* pb     = (const float*)d_in[9];
    const float* mw     = (const float*)d_in[10];
    const float* mb     = (const float*)d_in[11];
    float* out = (float*)d_out;

    float* ws     = (float*)d_ws;
    float* hi     = ws;                            // BB*DD           = 24576
    float* qk     = hi + BB * DD;                  // BB*NH*DD        = 98304
    float* scores = qk + BB * NH * DD;             // BB*NH*TT        = 524288
    float* part   = scores + (size_t)BB * NH * TT; // BB*NCHUNK*NH*DD = 1572864
    float* hbar   = part + (size_t)BB * NCHUNK * NH * DD;  // 98304
    float* pwT    = hbar + BB * NH * DD;           // INPROJ*HIDDEN   = 458752

    kA<<<BB * NH, 256, 0, stream>>>(H, noun, WQ, WK, hi, qk);
    kB<<<BB * (TT / TB), 256, 0, stream>>>(H, mask, noun, relb, qk, scores);
    kSM<<<BB * NH, 256, 0, stream>>>(scores);
    kC<<<BB * NCHUNK, 192, 0, stream>>>(H, scores, part);
    kComb<<<(BB * NH * DD) / 256, 256, 0, stream>>>(part, hbar);
    kT<<<(HIDDEN * INPROJ) / 256, 256, 0, stream>>>(pw, pwT);
    kD<<<BB, 256, 0, stream>>>(hbar, hi, pooled, WV, pwT, pb, mw, mb, out);
}

// Round 2
// 258.185 us; speedup vs baseline: 1.1098x; 1.1098x over previous
//
#include <hip/hip_runtime.h>
#include <math.h>

#define BB 32
#define TT 4096
#define DD 768
#define NH 4
#define DK 64
#define DV 64
#define RELW 32
#define NREL 65
#define HIDDEN 256
#define INPROJ 1792  // DD + NH*DV + DD

#define NCH 16                 // chunks per batch
#define CROWS (TT / NCH)       // 256 rows per chunk
#define TROWS 16               // rows per LDS tile
#define NTILES (CROWS / TROWS) // 16

// ---------------- kernel A: h_i gather, Q = h_i·WQ, qk = (Q·WK)/8 ----------------
__global__ __launch_bounds__(256) void kA(const float* __restrict__ H,
                                          const int* __restrict__ noun_pos,
                                          const float* __restrict__ WQ,
                                          const float* __restrict__ WK,
                                          float* __restrict__ hi_ws,
                                          float* __restrict__ qk_ws) {
    int b = blockIdx.x / NH, h = blockIdx.x % NH;
    __shared__ float hi_s[DD];
    __shared__ float q_s[DK];
    int tn = noun_pos[b];
    const float* Hrow = H + ((size_t)b * TT + tn) * DD;
    for (int d = threadIdx.x; d < DD; d += 256) {
        float v = Hrow[d];
        hi_s[d] = v;
        if (h == 0) hi_ws[b * DD + d] = v;
    }
    __syncthreads();
    if (threadIdx.x < DK) {
        int k = threadIdx.x;
        const float* wq = WQ + (size_t)h * DD * DK + k;
        float acc = 0.f;
        for (int d = 0; d < DD; ++d) acc += hi_s[d] * wq[(size_t)d * DK];
        q_s[k] = acc;
    }
    __syncthreads();
    for (int d = threadIdx.x; d < DD; d += 256) {
        const float* wk = WK + ((size_t)h * DD + d) * DK;
        float acc = 0.f;
        #pragma unroll
        for (int k = 0; k < DK; ++k) acc += q_s[k] * wk[k];
        qk_ws[((size_t)b * NH + h) * DD + d] = acc * 0.125f;  // 1/sqrt(64)
    }
}

// ---------------- kFlash: one pass over H — scores + online softmax + weighted sum ----------------
__global__ __launch_bounds__(256, 2) void kFlash(const float* __restrict__ H,
                                                 const int* __restrict__ mask,
                                                 const int* __restrict__ noun_pos,
                                                 const float* __restrict__ rel_bias,
                                                 const float* __restrict__ qk_ws,
                                                 float* __restrict__ macc,
                                                 float* __restrict__ ml) {
    int b  = blockIdx.x / NCH;
    int ch = blockIdx.x % NCH;
    int tid = threadIdx.x;
    int wave = tid >> 6, lane = tid & 63;

    __shared__ float Ht[TROWS * DD];     // 48 KB tile
    __shared__ float sL[TROWS][NH];
    __shared__ float rb_s[NH][NREL];

    for (int i = tid; i < NH * NREL; i += 256) ((float*)rb_s)[i] = rel_bias[i];

    // qk fragments in registers: qkr[h][j] = qk[b][h][4*(lane+64j) .. +3]
    float4 qkr[NH][3];
    const float4* qk4 = (const float4*)(qk_ws + (size_t)b * NH * DD);
    #pragma unroll
    for (int h = 0; h < NH; ++h)
        #pragma unroll
        for (int j = 0; j < 3; ++j)
            qkr[h][j] = qk4[h * (DD / 4) + lane + 64 * j];

    int tn = noun_pos[b];
    int t0 = ch * CROWS;

    float m[NH], l[NH], acc[NH][3];
    #pragma unroll
    for (int h = 0; h < NH; ++h) {
        m[h] = -3.0e38f; l[h] = 0.f;
        acc[h][0] = acc[h][1] = acc[h][2] = 0.f;
    }

    const float4* Hb4 = (const float4*)(H + ((size_t)b * TT + t0) * DD);
    float4* Ht4 = (float4*)Ht;

    for (int tile = 0; tile < NTILES; ++tile) {
        // ---- stage 16 rows (48 KB) into LDS, coalesced float4 ----
        const float4* src = Hb4 + (size_t)tile * TROWS * (DD / 4);
        #pragma unroll
        for (int i = 0; i < 12; ++i)
            Ht4[tid + 256 * i] = src[tid + 256 * i];
        __syncthreads();

        // ---- scores: wave w handles rows 4w..4w+3 ----
        #pragma unroll
        for (int k = 0; k < 4; ++k) {
            int r = wave * 4 + k;
            const float4* Hr = (const float4*)(Ht + r * DD);
            float s0 = 0.f, s1 = 0.f, s2 = 0.f, s3 = 0.f;
            #pragma unroll
            for (int j = 0; j < 3; ++j) {
                float4 hv = Hr[lane + 64 * j];
                s0 += hv.x*qkr[0][j].x + hv.y*qkr[0][j].y + hv.z*qkr[0][j].z + hv.w*qkr[0][j].w;
                s1 += hv.x*qkr[1][j].x + hv.y*qkr[1][j].y + hv.z*qkr[1][j].z + hv.w*qkr[1][j].w;
                s2 += hv.x*qkr[2][j].x + hv.y*qkr[2][j].y + hv.z*qkr[2][j].z + hv.w*qkr[2][j].w;
                s3 += hv.x*qkr[3][j].x + hv.y*qkr[3][j].y + hv.z*qkr[3][j].z + hv.w*qkr[3][j].w;
            }
            #pragma unroll
            for (int off = 32; off; off >>= 1) {
                s0 += __shfl_xor(s0, off); s1 += __shfl_xor(s1, off);
                s2 += __shfl_xor(s2, off); s3 += __shfl_xor(s3, off);
            }
            if (lane < NH) {
                int t = t0 + tile * TROWS + r;
                float s = lane == 0 ? s0 : lane == 1 ? s1 : lane == 2 ? s2 : s3;
                int dl = t - tn;
                dl = dl < -RELW ? -RELW : (dl > RELW ? RELW : dl);
                s += rb_s[lane][dl + RELW];
                if (mask[(size_t)b * TT + t] == 0) s = -1.0e9f;
                sL[r][lane] = s;
            }
        }
        __syncthreads();

        // ---- online softmax update (identical state on every thread) ----
        float p[NH][TROWS];
        #pragma unroll
        for (int h = 0; h < NH; ++h) {
            float tm = sL[0][h];
            #pragma unroll
            for (int r = 1; r < TROWS; ++r) tm = fmaxf(tm, sL[r][h]);
            float mn = fmaxf(m[h], tm);
            float sc = __expf(m[h] - mn);
            float ps = 0.f;
            #pragma unroll
            for (int r = 0; r < TROWS; ++r) { p[h][r] = __expf(sL[r][h] - mn); ps += p[h][r]; }
            l[h] = l[h] * sc + ps;
            m[h] = mn;
            acc[h][0] *= sc; acc[h][1] *= sc; acc[h][2] *= sc;
        }
        // ---- accumulate: thread owns d = tid + 256j ----
        #pragma unroll
        for (int j = 0; j < 3; ++j) {
            int dj = tid + 256 * j;
            float hv[TROWS];
            #pragma unroll
            for (int r = 0; r < TROWS; ++r) hv[r] = Ht[r * DD + dj];
            #pragma unroll
            for (int h = 0; h < NH; ++h) {
                float a = acc[h][j];
                #pragma unroll
                for (int r = 0; r < TROWS; ++r) a += p[h][r] * hv[r];
                acc[h][j] = a;
            }
        }
        __syncthreads();  // protect Ht before next stage
    }

    #pragma unroll
    for (int h = 0; h < NH; ++h)
        #pragma unroll
        for (int j = 0; j < 3; ++j)
            macc[((size_t)blockIdx.x * NH + h) * DD + tid + 256 * j] = acc[h][j];
    if (tid < NH) {
        ml[blockIdx.x * NH * 2 + tid * 2 + 0] = m[tid];
        ml[blockIdx.x * NH * 2 + tid * 2 + 1] = l[tid];
    }
}

// ---------------- transpose proj_w (HIDDEN,INPROJ) -> (INPROJ,HIDDEN) ----------------
__global__ __launch_bounds__(256) void kT(const float* __restrict__ pw,
                                          float* __restrict__ pwT) {
    int o = blockIdx.x * 256 + threadIdx.x;
    int j = o / INPROJ, i = o % INPROJ;
    pwT[(size_t)i * HIDDEN + j] = pw[o];
}

// ---------------- kD: flash-combine + c = hbar·WV + concat + GELU MLP + logits ----------------
__global__ __launch_bounds__(256) void kD(const float* __restrict__ macc,
                                          const float* __restrict__ ml,
                                          const float* __restrict__ hi_ws,
                                          const float* __restrict__ pooled,
                                          const float* __restrict__ WV,
                                          const float* __restrict__ pwT,
                                          const float* __restrict__ pb,
                                          const float* __restrict__ mw,
                                          const float* __restrict__ mb,
                                          float* __restrict__ out) {
    int b = blockIdx.x;
    __shared__ float w_s[NCH][NH];
    __shared__ float invL_s[NH];
    __shared__ float hb_s[NH * DD];
    __shared__ float r_s[INPROJ];
    __shared__ float hdn_s[HIDDEN];

    if (threadIdx.x < NH) {
        int h = threadIdx.x;
        float M = -3.0e38f;
        for (int c = 0; c < NCH; ++c)
            M = fmaxf(M, ml[((b * NCH + c) * NH + h) * 2 + 0]);
        float L = 0.f;
        for (int c = 0; c < NCH; ++c) {
            float w = __expf(ml[((b * NCH + c) * NH + h) * 2 + 0] - M);
            w_s[c][h] = w;
            L += w * ml[((b * NCH + c) * NH + h) * 2 + 1];
        }
        invL_s[h] = 1.f / L;
    }
    for (int i = threadIdx.x; i < DD; i += 256) {
        r_s[i] = hi_ws[b * DD + i];
        r_s[DD + NH * DV + i] = pooled[b * DD + i];
    }
    __syncthreads();
    // hbar combine (normalized)
    for (int i = threadIdx.x; i < NH * DD; i += 256) {
        int h = i / DD, d = i % DD;
        float a = 0.f;
        #pragma unroll
        for (int c = 0; c < NCH; ++c)
            a += w_s[c][h] * macc[((size_t)(b * NCH + c) * NH + h) * DD + d];
        hb_s[i] = a * invL_s[h];
    }
    __syncthreads();
    {   // c[h][v]; thread = h*64+v
        int h = threadIdx.x >> 6, v = threadIdx.x & 63;
        const float* wv = WV + (size_t)h * DD * DV + v;
        const float* hb = hb_s + h * DD;
        float acc = 0.f;
        for (int d = 0; d < DD; ++d) acc += hb[d] * wv[(size_t)d * DV];
        r_s[DD + threadIdx.x] = acc;
    }
    __syncthreads();
    {   // hidden j = tid
        int j = threadIdx.x;
        float acc = pb[j];
        #pragma unroll 8
        for (int i = 0; i < INPROJ; ++i) acc += r_s[i] * pwT[(size_t)i * HIDDEN + j];
        hdn_s[j] = 0.5f * acc * (1.f + erff(acc * 0.70710678118654752f));
    }
    __syncthreads();
    float p0 = hdn_s[threadIdx.x] * mw[threadIdx.x];
    float p1 = hdn_s[threadIdx.x] * mw[HIDDEN + threadIdx.x];
    #pragma unroll
    for (int off = 32; off; off >>= 1) {
        p0 += __shfl_xor(p0, off);
        p1 += __shfl_xor(p1, off);
    }
    __shared__ float r0[4], r1[4];
    if ((threadIdx.x & 63) == 0) {
        r0[threadIdx.x >> 6] = p0;
        r1[threadIdx.x >> 6] = p1;
    }
    __syncthreads();
    if (threadIdx.x == 0) {
        out[b * 2 + 0] = r0[0] + r0[1] + r0[2] + r0[3] + mb[0];
        out[b * 2 + 1] = r1[0] + r1[1] + r1[2] + r1[3] + mb[1];
    }
}

extern "C" void kernel_launch(void* const* d_in, const int* in_sizes, int n_in,
                              void* d_out, int out_size, void* d_ws, size_t ws_size,
                              hipStream_t stream) {
    const float* H      = (const float*)d_in[0];
    const int*   mask   = (const int*)d_in[1];
    const int*   noun   = (const int*)d_in[2];
    const float* pooled = (const float*)d_in[3];
    const float* WQ     = (const float*)d_in[4];
    const float* WK     = (const float*)d_in[5];
    const float* WV     = (const float*)d_in[6];
    const float* relb   = (const float*)d_in[7];
    const float* pw     = (const float*)d_in[8];
    const float* pb     = (const float*)d_in[9];
    const float* mw     = (const float*)d_in[10];
    const float* mb     = (const float*)d_in[11];
    float* out = (float*)d_out;

    float* ws   = (float*)d_ws;
    float* hi   = ws;                               // BB*DD            = 24576
    float* qk   = hi + BB * DD;                     // BB*NH*DD         = 98304
    float* macc = qk + BB * NH * DD;                // BB*NCH*NH*DD     = 1572864
    float* ml   = macc + (size_t)BB * NCH * NH * DD;// BB*NCH*NH*2      = 4096
    float* pwT  = ml + BB * NCH * NH * 2;           // INPROJ*HIDDEN    = 458752

    kA<<<BB * NH, 256, 0, stream>>>(H, noun, WQ, WK, hi, qk);
    kFlash<<<BB * NCH, 256, 0, stream>>>(H, mask, noun, relb, qk, macc, ml);
    kT<<<(HIDDEN * INPROJ) / 256, 256, 0, stream>>>(pw, pwT);
    kD<<<BB, 256, 0, stream>>>(macc, ml, hi, pooled, WV, pwT, pb, mw, mb, out);
}

// Round 3
// 235.153 us; speedup vs baseline: 1.2185x; 1.0979x over previous
//
#include <hip/hip_runtime.h>
#include <math.h>

#define BB 32
#define TT 4096
#define DD 768
#define NH 4
#define RELW 32
#define NREL 65
#define HIDDEN 256
#define INPROJ 1792  // DD + NH*64 + DD

#define NCH 16
#define CROWS 256              // rows per chunk (block)
#define TROWS 8                // rows per LDS tile
#define NT (CROWS / TROWS)     // 32 tiles
#define C4 (DD / 4)            // 192 float4 per row

#define BARRIER() __builtin_amdgcn_s_barrier()
#define FENCE_LGKM() asm volatile("s_waitcnt lgkmcnt(0)" ::: "memory")
#define WAITVM6() asm volatile("s_waitcnt vmcnt(6)" ::: "memory")
#define WAITVM0() asm volatile("s_waitcnt vmcnt(0)" ::: "memory")

// CK-style address-space casts (generic -> AS1/AS3 via uintptr_t)
__device__ __forceinline__ void gl_lds16(const float* g, float* l) {
    __builtin_amdgcn_global_load_lds(
        (const __attribute__((address_space(1))) float*)(uintptr_t)g,
        (__attribute__((address_space(3))) float*)(uintptr_t)l,
        16, 0, 0);
}

// ---------------- kernel A: h_i gather, Q = h_i*WQ, qk = (Q*WK)/8 ----------------
__global__ __launch_bounds__(256) void kA(const float* __restrict__ H,
                                          const int* __restrict__ noun_pos,
                                          const float* __restrict__ WQ,
                                          const float* __restrict__ WK,
                                          float* __restrict__ hi_ws,
                                          float* __restrict__ qk_ws) {
    int b = blockIdx.x / NH, h = blockIdx.x % NH;
    __shared__ float hi_s[DD];
    __shared__ float q_s[64];
    int tn = noun_pos[b];
    const float* Hrow = H + ((size_t)b * TT + tn) * DD;
    for (int d = threadIdx.x; d < DD; d += 256) {
        float v = Hrow[d];
        hi_s[d] = v;
        if (h == 0) hi_ws[b * DD + d] = v;
    }
    __syncthreads();
    if (threadIdx.x < 64) {
        int k = threadIdx.x;
        const float* wq = WQ + (size_t)h * DD * 64 + k;
        float acc = 0.f;
        for (int d = 0; d < DD; ++d) acc += hi_s[d] * wq[(size_t)d * 64];
        q_s[k] = acc;
    }
    __syncthreads();
    for (int d = threadIdx.x; d < DD; d += 256) {
        const float* wk = WK + ((size_t)h * DD + d) * 64;
        float acc = 0.f;
        #pragma unroll
        for (int k = 0; k < 64; ++k) acc += q_s[k] * wk[k];
        qk_ws[((size_t)b * NH + h) * DD + d] = acc * 0.125f;  // 1/sqrt(64)
    }
}

// ---------------- kFlash: single pass over H, async dbuf, online softmax ----------------
__global__ __launch_bounds__(256, 2) void kFlash(const float* __restrict__ H,
                                                 const int* __restrict__ mask,
                                                 const int* __restrict__ noun_pos,
                                                 const float* __restrict__ rel_bias,
                                                 const float* __restrict__ qk_ws,
                                                 float* __restrict__ macc,
                                                 float* __restrict__ ml) {
    const int b   = blockIdx.x / NCH;
    const int ch  = blockIdx.x % NCH;
    const int tid = threadIdx.x;
    const int wave = tid >> 6, lane = tid & 63;
    const int sl = lane >> 2, hh = lane & 3;   // 16 d-slices x 4 heads

    __shared__ float4 Hts[2][TROWS * C4];      // 2 x 24 KB double buffer
    __shared__ float4 rbL[CROWS];              // mask-folded rel bias per chunk row
    __shared__ __align__(16) float sL[TROWS * NH];

    const int t0 = ch * CROWS;
    const int tn = noun_pos[b];

    // fold mask + rel_bias for this chunk's 256 rows
    {
        int t = t0 + tid;
        int dl = t - tn; dl = dl < -RELW ? -RELW : (dl > RELW ? RELW : dl);
        int mm = mask[(size_t)b * TT + t];
        float4 rv;
        if (mm) {
            rv.x = rel_bias[0 * NREL + dl + RELW];
            rv.y = rel_bias[1 * NREL + dl + RELW];
            rv.z = rel_bias[2 * NREL + dl + RELW];
            rv.w = rel_bias[3 * NREL + dl + RELW];
        } else {
            rv.x = rv.y = rv.z = rv.w = -2.0e9f;
        }
        rbL[tid] = rv;
    }

    // qk fragment: head hh, d-positions {16j + sl}*4  (48 VGPRs)
    float4 qkr[12];
    {
        const float4* qk4 = (const float4*)(qk_ws + ((size_t)b * NH + hh) * DD);
        #pragma unroll
        for (int j = 0; j < 12; ++j) qkr[j] = qk4[j * 16 + sl];
    }

    const float* Hc = H + ((size_t)b * TT + t0) * DD;

    float m0 = -3.0e38f, m1 = -3.0e38f, m2 = -3.0e38f, m3 = -3.0e38f;
    float l0 = 0.f, l1 = 0.f, l2 = 0.f, l3 = 0.f;
    float4 a0 = {0.f,0.f,0.f,0.f}, a1 = {0.f,0.f,0.f,0.f};
    float4 a2 = {0.f,0.f,0.f,0.f}, a3 = {0.f,0.f,0.f,0.f};

    __syncthreads();   // rbL visible; vm drained -> clean vmcnt slate

    // prologue: stage tile 0 into buf 0 (6 insts/wave, 1KB each)
    {
        float* dst = (float*)&Hts[0][0];
        #pragma unroll
        for (int i = 0; i < 6; ++i) {
            int base = (wave * 6 + i) * 256;
            gl_lds16(Hc + base + lane * 4, dst + base);
        }
    }

    #pragma unroll 1
    for (int t = 0; t < NT; ++t) {
        const int cur = t & 1;
        // stage tile t+1 into other buffer; keep its 6 loads in flight
        if (t + 1 < NT) {
            const float* src = Hc + (size_t)(t + 1) * TROWS * DD;
            float* dst = (float*)&Hts[cur ^ 1][0];
            #pragma unroll
            for (int i = 0; i < 6; ++i) {
                int base = (wave * 6 + i) * 256;
                gl_lds16(src + base + lane * 4, dst + base);
            }
            WAITVM6();   // tile t's 6 loads complete; t+1's stay in flight
        } else {
            WAITVM0();
        }
        BARRIER();       // A: tile t resident for all waves

        const float4* Htc = &Hts[cur][0];
        // scores: wave handles rows 2w, 2w+1; 4 head-lanes share each read (broadcast)
        #pragma unroll
        for (int k = 0; k < 2; ++k) {
            const int r = wave * 2 + k;
            const float4* Hr = Htc + r * C4;
            float acc = 0.f;
            #pragma unroll
            for (int j = 0; j < 12; ++j) {
                float4 hv = Hr[j * 16 + sl];
                acc += hv.x * qkr[j].x + hv.y * qkr[j].y + hv.z * qkr[j].z + hv.w * qkr[j].w;
            }
            acc += __shfl_xor(acc, 4);
            acc += __shfl_xor(acc, 8);
            acc += __shfl_xor(acc, 16);
            acc += __shfl_xor(acc, 32);
            if (lane < NH)
                sL[r * NH + lane] = acc + ((const float*)&rbL[t * TROWS + r])[lane];
        }
        FENCE_LGKM();
        BARRIER();       // B: sL visible

        // online softmax, redundant per-thread (reads sL as 8 broadcast b128)
        float4 p4[TROWS];
        {
            const float4* sL4 = (const float4*)sL;
            #pragma unroll
            for (int r = 0; r < TROWS; ++r) p4[r] = sL4[r];
            float tx = p4[0].x, ty = p4[0].y, tz = p4[0].z, tw = p4[0].w;
            #pragma unroll
            for (int r = 1; r < TROWS; ++r) {
                tx = fmaxf(tx, p4[r].x); ty = fmaxf(ty, p4[r].y);
                tz = fmaxf(tz, p4[r].z); tw = fmaxf(tw, p4[r].w);
            }
            float n0 = fmaxf(m0, tx), n1 = fmaxf(m1, ty);
            float n2 = fmaxf(m2, tz), n3 = fmaxf(m3, tw);
            float s0 = __expf(m0 - n0), s1 = __expf(m1 - n1);
            float s2 = __expf(m2 - n2), s3 = __expf(m3 - n3);
            float q0 = 0.f, q1 = 0.f, q2 = 0.f, q3 = 0.f;
            #pragma unroll
            for (int r = 0; r < TROWS; ++r) {
                p4[r].x = __expf(p4[r].x - n0); q0 += p4[r].x;
                p4[r].y = __expf(p4[r].y - n1); q1 += p4[r].y;
                p4[r].z = __expf(p4[r].z - n2); q2 += p4[r].z;
                p4[r].w = __expf(p4[r].w - n3); q3 += p4[r].w;
            }
            l0 = l0 * s0 + q0; l1 = l1 * s1 + q1;
            l2 = l2 * s2 + q2; l3 = l3 * s3 + q3;
            m0 = n0; m1 = n1; m2 = n2; m3 = n3;
            a0.x *= s0; a0.y *= s0; a0.z *= s0; a0.w *= s0;
            a1.x *= s1; a1.y *= s1; a1.z *= s1; a1.w *= s1;
            a2.x *= s2; a2.y *= s2; a2.z *= s2; a2.w *= s2;
            a3.x *= s3; a3.y *= s3; a3.z *= s3; a3.w *= s3;
        }
        // accumulate: thread owns float4 column tid (192 active)
        if (tid < C4) {
            #pragma unroll
            for (int r = 0; r < TROWS; ++r) {
                float4 hv = Htc[r * C4 + tid];
                a0.x += p4[r].x * hv.x; a0.y += p4[r].x * hv.y; a0.z += p4[r].x * hv.z; a0.w += p4[r].x * hv.w;
                a1.x += p4[r].y * hv.x; a1.y += p4[r].y * hv.y; a1.z += p4[r].y * hv.z; a1.w += p4[r].y * hv.w;
                a2.x += p4[r].z * hv.x; a2.y += p4[r].z * hv.y; a2.z += p4[r].z * hv.z; a2.w += p4[r].z * hv.w;
                a3.x += p4[r].w * hv.x; a3.y += p4[r].w * hv.y; a3.z += p4[r].w * hv.z; a3.w += p4[r].w * hv.w;
            }
        }
        FENCE_LGKM();
        BARRIER();       // D: all reads drained; buffers/sL reusable
    }

    if (tid < C4) {
        float4* mo = (float4*)(macc + (size_t)blockIdx.x * NH * DD);
        mo[0 * C4 + tid] = a0;
        mo[1 * C4 + tid] = a1;
        mo[2 * C4 + tid] = a2;
        mo[3 * C4 + tid] = a3;
    }
    if (tid == 0) {
        float* mp = ml + (size_t)blockIdx.x * NH * 2;
        mp[0] = m0; mp[1] = l0; mp[2] = m1; mp[3] = l1;
        mp[4] = m2; mp[5] = l2; mp[6] = m3; mp[7] = l3;
    }
}

// ---------------- transpose proj_w (HIDDEN,INPROJ) -> (INPROJ,HIDDEN) ----------------
__global__ __launch_bounds__(256) void kT(const float* __restrict__ pw,
                                          float* __restrict__ pwT) {
    int o = blockIdx.x * 256 + threadIdx.x;
    int j = o / INPROJ, i = o % INPROJ;
    pwT[(size_t)i * HIDDEN + j] = pw[o];
}

// ---------------- kD: flash-combine + c = hbar*WV + concat + GELU MLP + logits ----------------
__global__ __launch_bounds__(256) void kD(const float* __restrict__ macc,
                                          const float* __restrict__ ml,
                                          const float* __restrict__ hi_ws,
                                          const float* __restrict__ pooled,
                                          const float* __restrict__ WV,
                                          const float* __restrict__ pwT,
                                          const float* __restrict__ pb,
                                          const float* __restrict__ mw,
                                          const float* __restrict__ mb,
                                          float* __restrict__ out) {
    int b = blockIdx.x;
    __shared__ float w_s[NCH][NH];
    __shared__ float invL_s[NH];
    __shared__ float hb_s[NH * DD];
    __shared__ float r_s[INPROJ];
    __shared__ float hdn_s[HIDDEN];

    if (threadIdx.x < NH) {
        int h = threadIdx.x;
        float M = -3.0e38f;
        for (int c = 0; c < NCH; ++c)
            M = fmaxf(M, ml[((b * NCH + c) * NH + h) * 2 + 0]);
        float L = 0.f;
        for (int c = 0; c < NCH; ++c) {
            float w = __expf(ml[((b * NCH + c) * NH + h) * 2 + 0] - M);
            w_s[c][h] = w;
            L += w * ml[((b * NCH + c) * NH + h) * 2 + 1];
        }
        invL_s[h] = 1.f / L;
    }
    for (int i = threadIdx.x; i < DD; i += 256) {
        r_s[i] = hi_ws[b * DD + i];
        r_s[DD + NH * 64 + i] = pooled[b * DD + i];
    }
    __syncthreads();
    for (int i = threadIdx.x; i < NH * DD; i += 256) {
        int h = i / DD, d = i % DD;
        float a = 0.f;
        #pragma unroll
        for (int c = 0; c < NCH; ++c)
            a += w_s[c][h] * macc[((size_t)(b * NCH + c) * NH + h) * DD + d];
        hb_s[i] = a * invL_s[h];
    }
    __syncthreads();
    {
        int h = threadIdx.x >> 6, v = threadIdx.x & 63;
        const float* wv = WV + (size_t)h * DD * 64 + v;
        const float* hb = hb_s + h * DD;
        float acc = 0.f;
        for (int d = 0; d < DD; ++d) acc += hb[d] * wv[(size_t)d * 64];
        r_s[DD + threadIdx.x] = acc;
    }
    __syncthreads();
    {
        int j = threadIdx.x;
        float acc = pb[j];
        #pragma unroll 8
        for (int i = 0; i < INPROJ; ++i) acc += r_s[i] * pwT[(size_t)i * HIDDEN + j];
        hdn_s[j] = 0.5f * acc * (1.f + erff(acc * 0.70710678118654752f));
    }
    __syncthreads();
    float p0 = hdn_s[threadIdx.x] * mw[threadIdx.x];
    float p1 = hdn_s[threadIdx.x] * mw[HIDDEN + threadIdx.x];
    #pragma unroll
    for (int off = 32; off; off >>= 1) {
        p0 += __shfl_xor(p0, off);
        p1 += __shfl_xor(p1, off);
    }
    __shared__ float r0[4], r1[4];
    if ((threadIdx.x & 63) == 0) {
        r0[threadIdx.x >> 6] = p0;
        r1[threadIdx.x >> 6] = p1;
    }
    __syncthreads();
    if (threadIdx.x == 0) {
        out[b * 2 + 0] = r0[0] + r0[1] + r0[2] + r0[3] + mb[0];
        out[b * 2 + 1] = r1[0] + r1[1] + r1[2] + r1[3] + mb[1];
    }
}

extern "C" void kernel_launch(void* const* d_in, const int* in_sizes, int n_in,
                              void* d_out, int out_size, void* d_ws, size_t ws_size,
                              hipStream_t stream) {
    const float* H      = (const float*)d_in[0];
    const int*   mask   = (const int*)d_in[1];
    const int*   noun   = (const int*)d_in[2];
    const float* pooled = (const float*)d_in[3];
    const float* WQ     = (const float*)d_in[4];
    const float* WK     = (const float*)d_in[5];
    const float* WV     = (const float*)d_in[6];
    const float* relb   = (const float*)d_in[7];
    const float* pw     = (const float*)d_in[8];
    const float* pb     = (const float*)d_in[9];
    const float* mw     = (const float*)d_in[10];
    const float* mb     = (const float*)d_in[11];
    float* out = (float*)d_out;

    float* ws   = (float*)d_ws;
    float* hi   = ws;                                // BB*DD         = 24576
    float* qk   = hi + BB * DD;                      // BB*NH*DD      = 98304
    float* macc = qk + BB * NH * DD;                 // BB*NCH*NH*DD  = 1572864
    float* ml   = macc + (size_t)BB * NCH * NH * DD; // BB*NCH*NH*2   = 4096
    float* pwT  = ml + BB * NCH * NH * 2;            // INPROJ*HIDDEN = 458752

    kA<<<BB * NH, 256, 0, stream>>>(H, noun, WQ, WK, hi, qk);
    kFlash<<<BB * NCH, 256, 0, stream>>>(H, mask, noun, relb, qk, macc, ml);
    kT<<<(HIDDEN * INPROJ) / 256, 256, 0, stream>>>(pw, pwT);
    kD<<<BB, 256, 0, stream>>>(macc, ml, hi, pooled, WV, pwT, pb, mw, mb, out);
}